// Round 6
// baseline (131.743 us; speedup 1.0000x reference)
//
#include <hip/hip_runtime.h>
#include <math.h>

#define EPSF 1e-9f

typedef float v4f __attribute__((ext_vector_type(4)));

// ws layout:
//   [0)        acc[4] floats: 0=id_num 1=id_cnt 2=kl_sum
//   [256)      agg_g   [256][64] float (64 KB)   -- zeroed each launch
//   [65792)    pmlog_g [256][64] float (64 KB)
//   [131328)   valid_g [256][64] float (64 KB)
//   [196864)   slot_map[256][4096] int8 (1 MB)
//   [1245440)  hot_idx [48*256] int (48 KB)

// ---------------------------------------------------------------------------
// Prep: per-b candidate dedup via direct-index table (RIDS=1024), Pm -> log,
// valid flags, and route->slot map for all 4096 v. grid 256 x 256.
// ---------------------------------------------------------------------------
__global__ __launch_bounds__(256) void e2e3_prep(
    const float* __restrict__ selector_probs,   // [256,64]
    const int*   __restrict__ candi_ids,        // [256,64]
    const int*   __restrict__ routes,           // [256,4096]
    float* __restrict__ pmlog_g,                // [256,64]
    float* __restrict__ valid_g,                // [256,64]
    signed char* __restrict__ slot_map)         // [256,4096]
{
    const int b   = blockIdx.x;
    const int tid = threadIdx.x;

    __shared__ int   ids_s[64];
    __shared__ int   table[1024];
    __shared__ int   rep_s[64];

    for (int i = tid; i < 1024; i += 256) table[i] = 64;    // sentinel
    if (tid < 64) ids_s[tid] = candi_ids[b * 64 + tid];
    __syncthreads();
    if (tid < 64) atomicMin(&table[ids_s[tid]], tid);       // first occurrence
    __syncthreads();
    if (tid < 64) {
        const int r = table[ids_s[tid]];
        rep_s[tid] = r;
        valid_g[b * 64 + tid] = (r == tid) ? 1.f : 0.f;
    }
    __syncthreads();
    if (tid < 64) {
        float pm = 0.f;
        for (int i = 0; i < 64; ++i)
            if (rep_s[i] == tid) pm += selector_probs[b * 64 + i];
        float tot = pm;
        #pragma unroll
        for (int off = 32; off >= 1; off >>= 1) tot += __shfl_xor(tot, off, 64);
        pm = pm / fmaxf(tot, EPSF);
        pmlog_g[b * 64 + tid] = logf(fmaxf(pm, EPSF));
    }

    // slot_map: thread tid covers v in [tid*16, tid*16+16)
    const int4* rp = reinterpret_cast<const int4*>(routes + (size_t)b * 4096 + tid * 16);
    signed char smv[16];
    #pragma unroll
    for (int j = 0; j < 4; ++j) {
        const int4 rv = rp[j];
        const int t0 = table[rv.x], t1 = table[rv.y], t2 = table[rv.z], t3 = table[rv.w];
        smv[j * 4 + 0] = (signed char)(t0 < 64 ? t0 : -1);
        smv[j * 4 + 1] = (signed char)(t1 < 64 ? t1 : -1);
        smv[j * 4 + 2] = (signed char)(t2 < 64 ? t2 : -1);
        smv[j * 4 + 3] = (signed char)(t3 < 64 ? t3 : -1);
    }
    *reinterpret_cast<int4*>(slot_map + (size_t)b * 4096 + tid * 16) =
        *reinterpret_cast<const int4*>(smv);
}

// ---------------------------------------------------------------------------
// Kernel A: pure nontemporal scan of trg_labels rows 1..48; one wave per
// 16 KB row; 16 unrolled dwordx4 nt loads (16 KB/wave in flight); extract
// the hot index (labels are exact one-hots). grid 3072 x 256 (4 waves/blk).
// ---------------------------------------------------------------------------
__global__ __launch_bounds__(256) void e2e3_hot(
    const float* __restrict__ trg_labels,   // [50,256,4096]
    int* __restrict__ hot_idx)              // [48*256]
{
    const int wave = threadIdx.x >> 6;
    const int lane = threadIdx.x & 63;
    const int row  = blockIdx.x * 4 + wave;     // [0,12288)
    const int t    = row >> 8;
    const int b    = row & 255;

    const size_t tstride = (size_t)256 * 4096;
    const float* p = trg_labels + (size_t)(t + 1) * tstride + (size_t)b * 4096;

    int hp = -1;
    #pragma unroll
    for (int j = 0; j < 16; ++j) {
        const int base = j * 256 + lane * 4;
        const v4f v = __builtin_nontemporal_load(
            reinterpret_cast<const v4f*>(p + base));
        if (v.x > 0.5f) hp = base;
        if (v.y > 0.5f) hp = base + 1;
        if (v.z > 0.5f) hp = base + 2;
        if (v.w > 0.5f) hp = base + 3;
    }
    #pragma unroll
    for (int off = 32; off >= 1; off >>= 1) {
        const int o = __shfl_xor(hp, off, 64);
        hp = (o > hp) ? o : hp;
    }
    if (lane == 0) hot_idx[row] = hp;
}

// ---------------------------------------------------------------------------
// Kernel B: single-stream scan of out_ids (normal loads -> L3-resident).
// grid 1024 (g = bid>>8, b = bid&255) x 512 thr; 12 t-rows, 32 B/thread/row,
// depth-2 prefetch. dist summed in registers over t, scattered once via
// slot_map into LDS agg -> agg_g. id-NLL: 12 gathered out[t][b][hot] scalars
// per block (issued early, L2-hot).
// ---------------------------------------------------------------------------
__global__ __launch_bounds__(512) void e2e3_dist(
    const float* __restrict__ out_ids,        // [48,256,4096]
    const signed char* __restrict__ slot_map, // [256,4096]
    const int*   __restrict__ hot_idx,        // [48*256]
    float* __restrict__ agg_g,                // [256,64]
    float* __restrict__ acc)
{
    const int bid  = blockIdx.x;
    const int b    = bid & 255;
    const int g    = bid >> 8;
    const int tid  = threadIdx.x;
    const int v0   = tid << 3;
    const int t0   = g * 12;

    __shared__ float agg_s[64];
    if (tid < 64) agg_s[tid] = 0.f;
    __syncthreads();

    const size_t tstride = (size_t)256 * 4096;

    // early gather for id-NLL: tid<12 handles t = t0+tid
    float gval = -1.f;
    if (tid < 12) {
        const int hid = hot_idx[(t0 + tid) * 256 + b];
        if (hid >= 0)
            gval = out_ids[(size_t)(t0 + tid) * tstride + (size_t)b * 4096 + hid];
    }

    const float* outp = out_ids + (size_t)t0 * tstride + (size_t)b * 4096 + v0;

    v4f d0 = (v4f)(0.f), d1 = (v4f)(0.f);
    v4f a0 = *reinterpret_cast<const v4f*>(outp);
    v4f a1 = *reinterpret_cast<const v4f*>(outp + 4);
    v4f b0 = *reinterpret_cast<const v4f*>(outp + tstride);
    v4f b1 = *reinterpret_cast<const v4f*>(outp + tstride + 4);

    for (int tt = 0; tt < 12; ++tt) {
        v4f n0 = (v4f)(0.f), n1 = (v4f)(0.f);
        if (tt < 10) {
            const size_t off = (size_t)(tt + 2) * tstride;
            n0 = *reinterpret_cast<const v4f*>(outp + off);
            n1 = *reinterpret_cast<const v4f*>(outp + off + 4);
        }
        d0 += a0;
        d1 += a1;
        a0 = b0; a1 = b1; b0 = n0; b1 = n1;
    }

    // scatter dist sums onto union slots via slot_map (8 bytes, one load)
    {
        const uint2 sv = *reinterpret_cast<const uint2*>(slot_map + (size_t)b * 4096 + v0);
        const unsigned int w0 = sv.x, w1 = sv.y;
        const float dv[8] = {d0.x, d0.y, d0.z, d0.w, d1.x, d1.y, d1.z, d1.w};
        #pragma unroll
        for (int j = 0; j < 4; ++j) {
            const int u0 = (int)(signed char)((w0 >> (8 * j)) & 0xFF);
            if (u0 >= 0) atomicAdd(&agg_s[u0], dv[j]);
            const int u1 = (int)(signed char)((w1 >> (8 * j)) & 0xFF);
            if (u1 >= 0) atomicAdd(&agg_s[u1], dv[4 + j]);
        }
    }

    // id-NLL reduce (contributors are lanes 0..11 of wave 0)
    float idnum = (gval >= 0.f) ? -logf(fmaxf(gval, EPSF)) : 0.f;
    float idcnt = (gval >= 0.f) ? 1.f : 0.f;
    if (tid < 64) {
        #pragma unroll
        for (int off = 32; off >= 1; off >>= 1) {
            idnum += __shfl_down(idnum, off, 64);
            idcnt += __shfl_down(idcnt, off, 64);
        }
        if (tid == 0 && (idnum != 0.f || idcnt != 0.f)) {
            atomicAdd(&acc[0], idnum);
            atomicAdd(&acc[1], idcnt);
        }
    }

    __syncthreads();
    if (tid < 64) atomicAdd(&agg_g[b * 64 + tid], agg_s[tid]);
}

// ---------------------------------------------------------------------------
// KL finalize: grid 256 x 64 (one wave per b).
// ---------------------------------------------------------------------------
__global__ __launch_bounds__(64) void e2e3_kl2(
    const float* __restrict__ agg_g,    // [256,64]
    const float* __restrict__ pmlog_g,  // [256,64]
    const float* __restrict__ valid_g,  // [256,64]
    float* __restrict__ acc)
{
    const int b = blockIdx.x;
    const int u = threadIdx.x;

    const float va = valid_g[b * 64 + u];
    const float a  = (va > 0.5f) ? agg_g[b * 64 + u] : 0.f;
    float s = a, uc = va;
    #pragma unroll
    for (int off = 32; off >= 1; off >>= 1) {
        s  += __shfl_xor(s,  off, 64);
        uc += __shfl_xor(uc, off, 64);
    }
    const float pb = (s > 0.f) ? (a / fmaxf(s, EPSF)) : (va / fmaxf(uc, 1.f));
    float term = 0.f;
    if (va > 0.5f) {
        const float pbc = fmaxf(pb, EPSF);
        term = pbc * (logf(pbc) - pmlog_g[b * 64 + u]);
    }
    #pragma unroll
    for (int off = 32; off >= 1; off >>= 1) term += __shfl_down(term, off, 64);
    if (u == 0) atomicAdd(&acc[2], term);
}

// ---------------------------------------------------------------------------
// Small terms + final combine. Single block, 256 threads.
// ---------------------------------------------------------------------------
__global__ __launch_bounds__(256) void e2e3_small(
    const float* __restrict__ selector_probs,   // [256,64]
    const float* __restrict__ selector_onehot,  // [256,64]
    const float* __restrict__ out_rates,        // [48,256]
    const float* __restrict__ trg_rates,        // [50,256]
    const int*   __restrict__ trg_lengths,      // [256]
    const float* __restrict__ acc,              // [4]
    float* __restrict__ out)
{
    const int tid  = threadIdx.x;
    const int wave = tid >> 6;
    const int lane = tid & 63;

    float v_selnum = 0.f, v_selcnt = 0.f, v_ent = 0.f;
    float v_rate = 0.f, v_den = 0.f, v_smooth = 0.f;

    for (int g = tid; g < 512; g += 256) {
        const float* pp = selector_probs  + g * 32;
        const float* oo = selector_onehot + g * 32;
        float p = 0.f, m = 0.f;
        #pragma unroll
        for (int k = 0; k < 32; ++k) { p += pp[k] * oo[k]; m += oo[k]; }
        if (m > 0.5f) { v_selnum += -logf(fmaxf(p, EPSF)); v_selcnt += 1.f; }
    }
    for (int i = tid; i < 256 * 64; i += 256) {
        const float p = fmaxf(selector_probs[i], EPSF);
        v_ent += -p * logf(p);
    }
    for (int i = tid; i < 48 * 256; i += 256)
        v_rate += fabsf(out_rates[i] - trg_rates[i + 256]);
    for (int b2 = tid; b2 < 256; b2 += 256)
        v_den += (float)(trg_lengths[b2] - 2);
    for (int i = tid; i < 47 * 256; i += 256) {
        const int b2 = i & 255;
        const int t  = i >> 8;
        int eff = trg_lengths[b2] - 3; if (eff < 0) eff = 0;
        if (t < eff) v_smooth += fabsf(out_rates[i + 256] - out_rates[i]);
    }

    __shared__ float red[6][4];
    float vals[6] = {v_selnum, v_selcnt, v_ent, v_rate, v_den, v_smooth};
    #pragma unroll
    for (int k = 0; k < 6; ++k) {
        float v = vals[k];
        #pragma unroll
        for (int off = 32; off >= 1; off >>= 1) v += __shfl_down(v, off, 64);
        if (lane == 0) red[k][wave] = v;
    }
    __syncthreads();
    if (tid == 0) {
        float s[6];
        #pragma unroll
        for (int k = 0; k < 6; ++k) s[k] = red[k][0] + red[k][1] + red[k][2] + red[k][3];
        const float loss =
              s[0] / fmaxf(s[1], 1.f)                      // LAM_SEL * loss_sel
            + 10.f * acc[0] / fmaxf(acc[1], 1.f)           // loss_id
            + 5.f  * s[3]   / fmaxf(s[4], 1.f)             // loss_rate
            + 0.1f * acc[2] * (1.f / 256.f)                // loss_kl
            + 0.05f * 0.5f * s[2] * (1.f / 256.f)          // loss_entropy
            + 0.5f * s[5];                                 // loss_smooth
        out[0] = loss;
    }
}

extern "C" void kernel_launch(void* const* d_in, const int* in_sizes, int n_in,
                              void* d_out, int out_size, void* d_ws, size_t ws_size,
                              hipStream_t stream) {
    const float* selector_probs  = (const float*)d_in[1];
    const float* selector_onehot = (const float*)d_in[2];
    const float* out_ids         = (const float*)d_in[3];
    const float* out_rates       = (const float*)d_in[4];
    const float* trg_labels      = (const float*)d_in[5];
    const float* trg_rates       = (const float*)d_in[6];
    const int*   trg_lengths     = (const int*)d_in[7];
    const int*   candi_ids       = (const int*)d_in[8];
    const int*   routes          = (const int*)d_in[9];

    char* ws = (char*)d_ws;
    float*       acc      = (float*)ws;                        // 16 B
    float*       agg_g    = (float*)(ws + 256);                // 64 KB
    float*       pmlog_g  = (float*)(ws + 256 + 65536);        // 64 KB
    float*       valid_g  = (float*)(ws + 256 + 131072);       // 64 KB
    signed char* slot_map = (signed char*)(ws + 196864);       // 1 MB
    int*         hot_idx  = (int*)(ws + 1245440);              // 48 KB

    // zero acc + agg_g
    (void)hipMemsetAsync(ws, 0, 256 + 65536, stream);

    e2e3_prep<<<256, 256, 0, stream>>>(selector_probs, candi_ids, routes,
                                       pmlog_g, valid_g, slot_map);
    e2e3_hot<<<3072, 256, 0, stream>>>(trg_labels, hot_idx);
    e2e3_dist<<<1024, 512, 0, stream>>>(out_ids, slot_map, hot_idx,
                                        agg_g, acc);
    e2e3_kl2<<<256, 64, 0, stream>>>(agg_g, pmlog_g, valid_g, acc);
    e2e3_small<<<1, 256, 0, stream>>>(selector_probs, selector_onehot,
                                      out_rates, trg_rates, trg_lengths,
                                      acc, (float*)d_out);
}

// Round 7
// 118.098 us; speedup vs baseline: 1.1155x; 1.1155x over previous
//
#include <hip/hip_runtime.h>
#include <math.h>

#define EPSF 1e-9f

typedef float v4f __attribute__((ext_vector_type(4)));

// ws layout:
//   [0)       acc[4] floats: 0=id_num 1=id_cnt 2=kl_sum   (zeroed by prep)
//   [256)     agg_g   [256][64] float (64 KB)             (zeroed by prep)
//   [65792)   pmlog_g [256][64] float (64 KB)
//   [131328)  valid_g [256][64] float (64 KB)
//   [196864)  slot_map[256][4096] int8 (1 MB)

// ---------------------------------------------------------------------------
// Prep: per-b candidate dedup via direct-index table (RIDS=1024), Pm -> log,
// valid flags, route->slot map, and zeroing of acc/agg_g. grid 256 x 256.
// ---------------------------------------------------------------------------
__global__ __launch_bounds__(256) void e2e3_prep(
    const float* __restrict__ selector_probs,   // [256,64]
    const int*   __restrict__ candi_ids,        // [256,64]
    const int*   __restrict__ routes,           // [256,4096]
    float* __restrict__ pmlog_g,                // [256,64]
    float* __restrict__ valid_g,                // [256,64]
    signed char* __restrict__ slot_map,         // [256,4096]
    float* __restrict__ agg_g,                  // [256,64]
    float* __restrict__ acc)                    // [4]
{
    const int b   = blockIdx.x;
    const int tid = threadIdx.x;

    __shared__ int   ids_s[64];
    __shared__ int   table[1024];
    __shared__ int   rep_s[64];

    // zero the accumulators this launch will use
    if (tid < 64) agg_g[b * 64 + tid] = 0.f;
    if (b == 0 && tid < 4) acc[tid] = 0.f;

    for (int i = tid; i < 1024; i += 256) table[i] = 64;    // sentinel
    if (tid < 64) ids_s[tid] = candi_ids[b * 64 + tid];
    __syncthreads();
    if (tid < 64) atomicMin(&table[ids_s[tid]], tid);       // first occurrence
    __syncthreads();
    if (tid < 64) {
        const int r = table[ids_s[tid]];
        rep_s[tid] = r;
        valid_g[b * 64 + tid] = (r == tid) ? 1.f : 0.f;
    }
    __syncthreads();
    if (tid < 64) {
        float pm = 0.f;
        for (int i = 0; i < 64; ++i)
            if (rep_s[i] == tid) pm += selector_probs[b * 64 + i];
        float tot = pm;
        #pragma unroll
        for (int off = 32; off >= 1; off >>= 1) tot += __shfl_xor(tot, off, 64);
        pm = pm / fmaxf(tot, EPSF);
        pmlog_g[b * 64 + tid] = logf(fmaxf(pm, EPSF));
    }

    // slot_map: thread tid covers v in [tid*16, tid*16+16)
    const int4* rp = reinterpret_cast<const int4*>(routes + (size_t)b * 4096 + tid * 16);
    signed char smv[16];
    #pragma unroll
    for (int j = 0; j < 4; ++j) {
        const int4 rv = rp[j];
        const int t0 = table[rv.x], t1 = table[rv.y], t2 = table[rv.z], t3 = table[rv.w];
        smv[j * 4 + 0] = (signed char)(t0 < 64 ? t0 : -1);
        smv[j * 4 + 1] = (signed char)(t1 < 64 ? t1 : -1);
        smv[j * 4 + 2] = (signed char)(t2 < 64 ? t2 : -1);
        smv[j * 4 + 3] = (signed char)(t3 < 64 ? t3 : -1);
    }
    *reinterpret_cast<int4*>(slot_map + (size_t)b * 4096 + tid * 16) =
        *reinterpret_cast<const int4*>(smv);
}

// ---------------------------------------------------------------------------
// Stream: grid 1024 (g = bid>>8, b = bid&255) x 512 thr; 12 t-rows per block,
// 32 B per thread per row per tensor, depth-1 prefetch. ALL loads are
// NONTEMPORAL (no-allocate): theory is that allocating reads through a
// thrashing 256 MB MALL halve effective read BW; nt makes this a pure HBM
// stream like the 7 TB/s fills. One-hot labels: dot == value at hot
// position. dist sums scatter via slot_map into LDS agg -> agg_g.
// ---------------------------------------------------------------------------
__global__ __launch_bounds__(512) void e2e3_stream(
    const float* __restrict__ out_ids,      // [48,256,4096]
    const float* __restrict__ trg_labels,   // [50,256,4096]
    const signed char* __restrict__ slot_map, // [256,4096]
    float* __restrict__ agg_g,              // [256,64]
    float* __restrict__ acc)
{
    const int bid  = blockIdx.x;
    const int b    = bid & 255;
    const int g    = bid >> 8;
    const int tid  = threadIdx.x;
    const int wave = tid >> 6;
    const int lane = tid & 63;
    const int v0   = tid << 3;
    const int t0   = g * 12;

    __shared__ float agg_s[64];
    __shared__ float red[2][8];
    if (tid < 64) agg_s[tid] = 0.f;
    __syncthreads();

    const size_t tstride = (size_t)256 * 4096;
    const float* outp = out_ids    + (size_t)t0 * tstride       + (size_t)b * 4096 + v0;
    const float* labp = trg_labels + (size_t)(t0 + 1) * tstride + (size_t)b * 4096 + v0;

    v4f d0 = (v4f)(0.f);
    v4f d1 = (v4f)(0.f);
    float idnum = 0.f, idcnt = 0.f;

    v4f o0 = __builtin_nontemporal_load(reinterpret_cast<const v4f*>(outp));
    v4f o1 = __builtin_nontemporal_load(reinterpret_cast<const v4f*>(outp + 4));
    v4f l0 = __builtin_nontemporal_load(reinterpret_cast<const v4f*>(labp));
    v4f l1 = __builtin_nontemporal_load(reinterpret_cast<const v4f*>(labp + 4));

    for (int t = 0; t < 12; ++t) {
        v4f no0 = o0, no1 = o1, nl0 = l0, nl1 = l1;
        if (t < 11) {
            const size_t off = (size_t)(t + 1) * tstride;
            no0 = __builtin_nontemporal_load(reinterpret_cast<const v4f*>(outp + off));
            no1 = __builtin_nontemporal_load(reinterpret_cast<const v4f*>(outp + off + 4));
            nl0 = __builtin_nontemporal_load(reinterpret_cast<const v4f*>(labp + off));
            nl1 = __builtin_nontemporal_load(reinterpret_cast<const v4f*>(labp + off + 4));
        }
        d0 += o0;
        d1 += o1;
        if (l0.x > 0.5f) { idnum -= logf(fmaxf(o0.x, EPSF)); idcnt += 1.f; }
        if (l0.y > 0.5f) { idnum -= logf(fmaxf(o0.y, EPSF)); idcnt += 1.f; }
        if (l0.z > 0.5f) { idnum -= logf(fmaxf(o0.z, EPSF)); idcnt += 1.f; }
        if (l0.w > 0.5f) { idnum -= logf(fmaxf(o0.w, EPSF)); idcnt += 1.f; }
        if (l1.x > 0.5f) { idnum -= logf(fmaxf(o1.x, EPSF)); idcnt += 1.f; }
        if (l1.y > 0.5f) { idnum -= logf(fmaxf(o1.y, EPSF)); idcnt += 1.f; }
        if (l1.z > 0.5f) { idnum -= logf(fmaxf(o1.z, EPSF)); idcnt += 1.f; }
        if (l1.w > 0.5f) { idnum -= logf(fmaxf(o1.w, EPSF)); idcnt += 1.f; }
        o0 = no0; o1 = no1; l0 = nl0; l1 = nl1;
    }

    // scatter dist sums onto union slots via slot_map (8 bytes, one load)
    {
        const uint2 sv = *reinterpret_cast<const uint2*>(slot_map + (size_t)b * 4096 + v0);
        const unsigned int w0 = sv.x, w1 = sv.y;
        const float dv[8] = {d0.x, d0.y, d0.z, d0.w, d1.x, d1.y, d1.z, d1.w};
        #pragma unroll
        for (int j = 0; j < 4; ++j) {
            const int u0 = (int)(signed char)((w0 >> (8 * j)) & 0xFF);
            if (u0 >= 0) atomicAdd(&agg_s[u0], dv[j]);
            const int u1 = (int)(signed char)((w1 >> (8 * j)) & 0xFF);
            if (u1 >= 0) atomicAdd(&agg_s[u1], dv[4 + j]);
        }
    }

    #pragma unroll
    for (int off = 32; off >= 1; off >>= 1) {
        idnum += __shfl_down(idnum, off, 64);
        idcnt += __shfl_down(idcnt, off, 64);
    }
    if (lane == 0) { red[0][wave] = idnum; red[1][wave] = idcnt; }
    __syncthreads();
    if (tid == 0) {
        float a = 0.f, c = 0.f;
        #pragma unroll
        for (int w = 0; w < 8; ++w) { a += red[0][w]; c += red[1][w]; }
        atomicAdd(&acc[0], a);
        atomicAdd(&acc[1], c);
    }
    if (tid < 64) atomicAdd(&agg_g[b * 64 + tid], agg_s[tid]);
}

// ---------------------------------------------------------------------------
// KL finalize: grid 256 x 64 (one wave per b).
// ---------------------------------------------------------------------------
__global__ __launch_bounds__(64) void e2e3_kl2(
    const float* __restrict__ agg_g,    // [256,64]
    const float* __restrict__ pmlog_g,  // [256,64]
    const float* __restrict__ valid_g,  // [256,64]
    float* __restrict__ acc)
{
    const int b = blockIdx.x;
    const int u = threadIdx.x;

    const float va = valid_g[b * 64 + u];
    const float a  = (va > 0.5f) ? agg_g[b * 64 + u] : 0.f;
    float s = a, uc = va;
    #pragma unroll
    for (int off = 32; off >= 1; off >>= 1) {
        s  += __shfl_xor(s,  off, 64);
        uc += __shfl_xor(uc, off, 64);
    }
    const float pb = (s > 0.f) ? (a / fmaxf(s, EPSF)) : (va / fmaxf(uc, 1.f));
    float term = 0.f;
    if (va > 0.5f) {
        const float pbc = fmaxf(pb, EPSF);
        term = pbc * (logf(pbc) - pmlog_g[b * 64 + u]);
    }
    #pragma unroll
    for (int off = 32; off >= 1; off >>= 1) term += __shfl_down(term, off, 64);
    if (u == 0) atomicAdd(&acc[2], term);
}

// ---------------------------------------------------------------------------
// Small terms + final combine. Single block, 256 threads.
// ---------------------------------------------------------------------------
__global__ __launch_bounds__(256) void e2e3_small(
    const float* __restrict__ selector_probs,   // [256,64]
    const float* __restrict__ selector_onehot,  // [256,64]
    const float* __restrict__ out_rates,        // [48,256]
    const float* __restrict__ trg_rates,        // [50,256]
    const int*   __restrict__ trg_lengths,      // [256]
    const float* __restrict__ acc,              // [4]
    float* __restrict__ out)
{
    const int tid  = threadIdx.x;
    const int wave = tid >> 6;
    const int lane = tid & 63;

    float v_selnum = 0.f, v_selcnt = 0.f, v_ent = 0.f;
    float v_rate = 0.f, v_den = 0.f, v_smooth = 0.f;

    for (int g = tid; g < 512; g += 256) {
        const float* pp = selector_probs  + g * 32;
        const float* oo = selector_onehot + g * 32;
        float p = 0.f, m = 0.f;
        #pragma unroll
        for (int k = 0; k < 32; ++k) { p += pp[k] * oo[k]; m += oo[k]; }
        if (m > 0.5f) { v_selnum += -logf(fmaxf(p, EPSF)); v_selcnt += 1.f; }
    }
    for (int i = tid; i < 256 * 64; i += 256) {
        const float p = fmaxf(selector_probs[i], EPSF);
        v_ent += -p * logf(p);
    }
    for (int i = tid; i < 48 * 256; i += 256)
        v_rate += fabsf(out_rates[i] - trg_rates[i + 256]);
    for (int b2 = tid; b2 < 256; b2 += 256)
        v_den += (float)(trg_lengths[b2] - 2);
    for (int i = tid; i < 47 * 256; i += 256) {
        const int b2 = i & 255;
        const int t  = i >> 8;
        int eff = trg_lengths[b2] - 3; if (eff < 0) eff = 0;
        if (t < eff) v_smooth += fabsf(out_rates[i + 256] - out_rates[i]);
    }

    __shared__ float red[6][4];
    float vals[6] = {v_selnum, v_selcnt, v_ent, v_rate, v_den, v_smooth};
    #pragma unroll
    for (int k = 0; k < 6; ++k) {
        float v = vals[k];
        #pragma unroll
        for (int off = 32; off >= 1; off >>= 1) v += __shfl_down(v, off, 64);
        if (lane == 0) red[k][wave] = v;
    }
    __syncthreads();
    if (tid == 0) {
        float s[6];
        #pragma unroll
        for (int k = 0; k < 6; ++k) s[k] = red[k][0] + red[k][1] + red[k][2] + red[k][3];
        const float loss =
              s[0] / fmaxf(s[1], 1.f)                      // LAM_SEL * loss_sel
            + 10.f * acc[0] / fmaxf(acc[1], 1.f)           // loss_id
            + 5.f  * s[3]   / fmaxf(s[4], 1.f)             // loss_rate
            + 0.1f * acc[2] * (1.f / 256.f)                // loss_kl
            + 0.05f * 0.5f * s[2] * (1.f / 256.f)          // loss_entropy
            + 0.5f * s[5];                                 // loss_smooth
        out[0] = loss;
    }
}

extern "C" void kernel_launch(void* const* d_in, const int* in_sizes, int n_in,
                              void* d_out, int out_size, void* d_ws, size_t ws_size,
                              hipStream_t stream) {
    const float* selector_probs  = (const float*)d_in[1];
    const float* selector_onehot = (const float*)d_in[2];
    const float* out_ids         = (const float*)d_in[3];
    const float* out_rates       = (const float*)d_in[4];
    const float* trg_labels      = (const float*)d_in[5];
    const float* trg_rates       = (const float*)d_in[6];
    const int*   trg_lengths     = (const int*)d_in[7];
    const int*   candi_ids       = (const int*)d_in[8];
    const int*   routes          = (const int*)d_in[9];

    char* ws = (char*)d_ws;
    float*       acc      = (float*)ws;                    // 16 B
    float*       agg_g    = (float*)(ws + 256);            // 64 KB
    float*       pmlog_g  = (float*)(ws + 256 + 65536);    // 64 KB
    float*       valid_g  = (float*)(ws + 256 + 131072);   // 64 KB
    signed char* slot_map = (signed char*)(ws + 196864);   // 1 MB

    e2e3_prep<<<256, 256, 0, stream>>>(selector_probs, candi_ids, routes,
                                       pmlog_g, valid_g, slot_map,
                                       agg_g, acc);
    e2e3_stream<<<1024, 512, 0, stream>>>(out_ids, trg_labels, slot_map,
                                          agg_g, acc);
    e2e3_kl2<<<256, 64, 0, stream>>>(agg_g, pmlog_g, valid_g, acc);
    e2e3_small<<<1, 256, 0, stream>>>(selector_probs, selector_onehot,
                                      out_rates, trg_rates, trg_lengths,
                                      acc, (float*)d_out);
}

// Round 8
// 116.273 us; speedup vs baseline: 1.1331x; 1.0157x over previous
//
#include <hip/hip_runtime.h>
#include <math.h>

#define EPSF 1e-9f

typedef float v4f __attribute__((ext_vector_type(4)));

// ws layout:
//   [0)       acc[4] floats: 0=id_num 1=id_cnt 2=kl_sum   (zeroed by prep)
//   [256)     agg_g   [256][64] float (64 KB)             (zeroed by prep)
//   [65792)   pmlog_g [256][64] float (64 KB)
//   [131328)  valid_g [256][64] float (64 KB)
//   [196864)  slot_map[256][4096] int8 (1 MB)

// ---------------------------------------------------------------------------
// Prep: per-b candidate dedup via direct-index table (RIDS=1024), Pm -> log,
// valid flags, route->slot map, and zeroing of acc/agg_g. grid 256 x 256.
// ---------------------------------------------------------------------------
__global__ __launch_bounds__(256) void e2e3_prep(
    const float* __restrict__ selector_probs,   // [256,64]
    const int*   __restrict__ candi_ids,        // [256,64]
    const int*   __restrict__ routes,           // [256,4096]
    float* __restrict__ pmlog_g,                // [256,64]
    float* __restrict__ valid_g,                // [256,64]
    signed char* __restrict__ slot_map,         // [256,4096]
    float* __restrict__ agg_g,                  // [256,64]
    float* __restrict__ acc)                    // [4]
{
    const int b   = blockIdx.x;
    const int tid = threadIdx.x;

    __shared__ int   ids_s[64];
    __shared__ int   table[1024];
    __shared__ int   rep_s[64];

    if (tid < 64) agg_g[b * 64 + tid] = 0.f;
    if (b == 0 && tid < 4) acc[tid] = 0.f;

    for (int i = tid; i < 1024; i += 256) table[i] = 64;    // sentinel
    if (tid < 64) ids_s[tid] = candi_ids[b * 64 + tid];
    __syncthreads();
    if (tid < 64) atomicMin(&table[ids_s[tid]], tid);       // first occurrence
    __syncthreads();
    if (tid < 64) {
        const int r = table[ids_s[tid]];
        rep_s[tid] = r;
        valid_g[b * 64 + tid] = (r == tid) ? 1.f : 0.f;
    }
    __syncthreads();
    if (tid < 64) {
        float pm = 0.f;
        for (int i = 0; i < 64; ++i)
            if (rep_s[i] == tid) pm += selector_probs[b * 64 + i];
        float tot = pm;
        #pragma unroll
        for (int off = 32; off >= 1; off >>= 1) tot += __shfl_xor(tot, off, 64);
        pm = pm / fmaxf(tot, EPSF);
        pmlog_g[b * 64 + tid] = logf(fmaxf(pm, EPSF));
    }

    // slot_map: thread tid covers v in [tid*16, tid*16+16)
    const int4* rp = reinterpret_cast<const int4*>(routes + (size_t)b * 4096 + tid * 16);
    signed char smv[16];
    #pragma unroll
    for (int j = 0; j < 4; ++j) {
        const int4 rv = rp[j];
        const int t0 = table[rv.x], t1 = table[rv.y], t2 = table[rv.z], t3 = table[rv.w];
        smv[j * 4 + 0] = (signed char)(t0 < 64 ? t0 : -1);
        smv[j * 4 + 1] = (signed char)(t1 < 64 ? t1 : -1);
        smv[j * 4 + 2] = (signed char)(t2 < 64 ? t2 : -1);
        smv[j * 4 + 3] = (signed char)(t3 < 64 ? t3 : -1);
    }
    *reinterpret_cast<int4*>(slot_map + (size_t)b * 4096 + tid * 16) =
        *reinterpret_cast<const int4*>(smv);
}

// ---------------------------------------------------------------------------
// Stream: GRID-STRIDE LINEAR (copy-bench shaped). 1024 blocks x 512 thr,
// exactly co-resident (4 blocks/CU). Thread's element e = gtid*4 + s*2M
// floats; per-step advance = 2M floats = 512 rows = 2 t-slabs -> (b,v) fixed
// per lane for all 24 steps. The whole GPU marches ONE contiguous window per
// tensor (max DRAM row locality). Labels pair at e + 1 slab (t+1, same b,v):
// one-hot => NLL value is the same lane's out float4, no gather needed.
// Slot bytes loaded once per lane; ~6% valid => LDS atomics negligible.
// out_ids: normal loads (L3-resident upside). trg_labels: nontemporal.
// ---------------------------------------------------------------------------
__global__ __launch_bounds__(512) void e2e3_stream(
    const float* __restrict__ out_ids,        // [48,256,4096]
    const float* __restrict__ trg_labels,     // [50,256,4096]
    const signed char* __restrict__ slot_map, // [256,4096]
    float* __restrict__ agg_g,                // [256,64]
    float* __restrict__ acc)
{
    const int bid  = blockIdx.x;
    const int tid  = threadIdx.x;
    const int wave = tid >> 6;
    const int lane = tid & 63;

    const int b = (bid >> 1) & 255;                 // constant per block
    const int v = (bid & 1) * 2048 + tid * 4;       // constant per lane

    __shared__ float agg_s[64];
    __shared__ float red[2][8];
    if (tid < 64) agg_s[tid] = 0.f;
    __syncthreads();

    // slot bytes for this lane's 4 v-positions (fixed for all steps)
    const unsigned int sm =
        *reinterpret_cast<const unsigned int*>(slot_map + (size_t)b * 4096 + v);
    const int u0 = (int)(signed char)(sm & 0xFF);
    const int u1 = (int)(signed char)((sm >> 8) & 0xFF);
    const int u2 = (int)(signed char)((sm >> 16) & 0xFF);
    const int u3 = (int)(signed char)((sm >> 24) & 0xFF);

    const size_t STEP = (size_t)2097152;            // floats per step (2 t-slabs)
    const size_t e0   = (size_t)(bid * 512 + tid) * 4;
    const float* op = out_ids + e0;
    const float* lp = trg_labels + e0 + 1048576;    // +1 t-slab => row t+1

    float s0 = 0.f, s1 = 0.f, s2 = 0.f, s3 = 0.f;   // per-lane dist partials
    float idnum = 0.f, idcnt = 0.f;

    v4f oa = *reinterpret_cast<const v4f*>(op);
    v4f la = __builtin_nontemporal_load(reinterpret_cast<const v4f*>(lp));
    v4f ob = *reinterpret_cast<const v4f*>(op + STEP);
    v4f lb = __builtin_nontemporal_load(reinterpret_cast<const v4f*>(lp + STEP));

    for (int s = 0; s < 24; ++s) {
        v4f oc = (v4f)(0.f), lc = (v4f)(0.f);
        if (s < 22) {
            oc = *reinterpret_cast<const v4f*>(op + (size_t)(s + 2) * STEP);
            lc = __builtin_nontemporal_load(
                     reinterpret_cast<const v4f*>(lp + (size_t)(s + 2) * STEP));
        }
        s0 += oa.x; s1 += oa.y; s2 += oa.z; s3 += oa.w;
        if (la.x > 0.5f) { idnum -= logf(fmaxf(oa.x, EPSF)); idcnt += 1.f; }
        if (la.y > 0.5f) { idnum -= logf(fmaxf(oa.y, EPSF)); idcnt += 1.f; }
        if (la.z > 0.5f) { idnum -= logf(fmaxf(oa.z, EPSF)); idcnt += 1.f; }
        if (la.w > 0.5f) { idnum -= logf(fmaxf(oa.w, EPSF)); idcnt += 1.f; }
        oa = ob; la = lb; ob = oc; lb = lc;
    }

    // scatter per-lane dist sums (valid slots only, ~6% density)
    if (u0 >= 0) atomicAdd(&agg_s[u0], s0);
    if (u1 >= 0) atomicAdd(&agg_s[u1], s1);
    if (u2 >= 0) atomicAdd(&agg_s[u2], s2);
    if (u3 >= 0) atomicAdd(&agg_s[u3], s3);

    #pragma unroll
    for (int off = 32; off >= 1; off >>= 1) {
        idnum += __shfl_down(idnum, off, 64);
        idcnt += __shfl_down(idcnt, off, 64);
    }
    if (lane == 0) { red[0][wave] = idnum; red[1][wave] = idcnt; }
    __syncthreads();
    if (tid == 0) {
        float a = 0.f, c = 0.f;
        #pragma unroll
        for (int w = 0; w < 8; ++w) { a += red[0][w]; c += red[1][w]; }
        atomicAdd(&acc[0], a);
        atomicAdd(&acc[1], c);
    }
    if (tid < 64) atomicAdd(&agg_g[b * 64 + tid], agg_s[tid]);
}

// ---------------------------------------------------------------------------
// KL finalize: grid 256 x 64 (one wave per b).
// ---------------------------------------------------------------------------
__global__ __launch_bounds__(64) void e2e3_kl2(
    const float* __restrict__ agg_g,    // [256,64]
    const float* __restrict__ pmlog_g,  // [256,64]
    const float* __restrict__ valid_g,  // [256,64]
    float* __restrict__ acc)
{
    const int b = blockIdx.x;
    const int u = threadIdx.x;

    const float va = valid_g[b * 64 + u];
    const float a  = (va > 0.5f) ? agg_g[b * 64 + u] : 0.f;
    float s = a, uc = va;
    #pragma unroll
    for (int off = 32; off >= 1; off >>= 1) {
        s  += __shfl_xor(s,  off, 64);
        uc += __shfl_xor(uc, off, 64);
    }
    const float pb = (s > 0.f) ? (a / fmaxf(s, EPSF)) : (va / fmaxf(uc, 1.f));
    float term = 0.f;
    if (va > 0.5f) {
        const float pbc = fmaxf(pb, EPSF);
        term = pbc * (logf(pbc) - pmlog_g[b * 64 + u]);
    }
    #pragma unroll
    for (int off = 32; off >= 1; off >>= 1) term += __shfl_down(term, off, 64);
    if (u == 0) atomicAdd(&acc[2], term);
}

// ---------------------------------------------------------------------------
// Small terms + final combine. Single block, 256 threads.
// ---------------------------------------------------------------------------
__global__ __launch_bounds__(256) void e2e3_small(
    const float* __restrict__ selector_probs,   // [256,64]
    const float* __restrict__ selector_onehot,  // [256,64]
    const float* __restrict__ out_rates,        // [48,256]
    const float* __restrict__ trg_rates,        // [50,256]
    const int*   __restrict__ trg_lengths,      // [256]
    const float* __restrict__ acc,              // [4]
    float* __restrict__ out)
{
    const int tid  = threadIdx.x;
    const int wave = tid >> 6;
    const int lane = tid & 63;

    float v_selnum = 0.f, v_selcnt = 0.f, v_ent = 0.f;
    float v_rate = 0.f, v_den = 0.f, v_smooth = 0.f;

    for (int g = tid; g < 512; g += 256) {
        const float* pp = selector_probs  + g * 32;
        const float* oo = selector_onehot + g * 32;
        float p = 0.f, m = 0.f;
        #pragma unroll
        for (int k = 0; k < 32; ++k) { p += pp[k] * oo[k]; m += oo[k]; }
        if (m > 0.5f) { v_selnum += -logf(fmaxf(p, EPSF)); v_selcnt += 1.f; }
    }
    for (int i = tid; i < 256 * 64; i += 256) {
        const float p = fmaxf(selector_probs[i], EPSF);
        v_ent += -p * logf(p);
    }
    for (int i = tid; i < 48 * 256; i += 256)
        v_rate += fabsf(out_rates[i] - trg_rates[i + 256]);
    for (int b2 = tid; b2 < 256; b2 += 256)
        v_den += (float)(trg_lengths[b2] - 2);
    for (int i = tid; i < 47 * 256; i += 256) {
        const int b2 = i & 255;
        const int t  = i >> 8;
        int eff = trg_lengths[b2] - 3; if (eff < 0) eff = 0;
        if (t < eff) v_smooth += fabsf(out_rates[i + 256] - out_rates[i]);
    }

    __shared__ float red[6][4];
    float vals[6] = {v_selnum, v_selcnt, v_ent, v_rate, v_den, v_smooth};
    #pragma unroll
    for (int k = 0; k < 6; ++k) {
        float v = vals[k];
        #pragma unroll
        for (int off = 32; off >= 1; off >>= 1) v += __shfl_down(v, off, 64);
        if (lane == 0) red[k][wave] = v;
    }
    __syncthreads();
    if (tid == 0) {
        float s[6];
        #pragma unroll
        for (int k = 0; k < 6; ++k) s[k] = red[k][0] + red[k][1] + red[k][2] + red[k][3];
        const float loss =
              s[0] / fmaxf(s[1], 1.f)                      // LAM_SEL * loss_sel
            + 10.f * acc[0] / fmaxf(acc[1], 1.f)           // loss_id
            + 5.f  * s[3]   / fmaxf(s[4], 1.f)             // loss_rate
            + 0.1f * acc[2] * (1.f / 256.f)                // loss_kl
            + 0.05f * 0.5f * s[2] * (1.f / 256.f)          // loss_entropy
            + 0.5f * s[5];                                 // loss_smooth
        out[0] = loss;
    }
}

extern "C" void kernel_launch(void* const* d_in, const int* in_sizes, int n_in,
                              void* d_out, int out_size, void* d_ws, size_t ws_size,
                              hipStream_t stream) {
    const float* selector_probs  = (const float*)d_in[1];
    const float* selector_onehot = (const float*)d_in[2];
    const float* out_ids         = (const float*)d_in[3];
    const float* out_rates       = (const float*)d_in[4];
    const float* trg_labels      = (const float*)d_in[5];
    const float* trg_rates       = (const float*)d_in[6];
    const int*   trg_lengths     = (const int*)d_in[7];
    const int*   candi_ids       = (const int*)d_in[8];
    const int*   routes          = (const int*)d_in[9];

    char* ws = (char*)d_ws;
    float*       acc      = (float*)ws;                    // 16 B
    float*       agg_g    = (float*)(ws + 256);            // 64 KB
    float*       pmlog_g  = (float*)(ws + 256 + 65536);    // 64 KB
    float*       valid_g  = (float*)(ws + 256 + 131072);   // 64 KB
    signed char* slot_map = (signed char*)(ws + 196864);   // 1 MB

    e2e3_prep<<<256, 256, 0, stream>>>(selector_probs, candi_ids, routes,
                                       pmlog_g, valid_g, slot_map,
                                       agg_g, acc);
    e2e3_stream<<<1024, 512, 0, stream>>>(out_ids, trg_labels, slot_map,
                                          agg_g, acc);
    e2e3_kl2<<<256, 64, 0, stream>>>(agg_g, pmlog_g, valid_g, acc);
    e2e3_small<<<1, 256, 0, stream>>>(selector_probs, selector_onehot,
                                      out_rates, trg_rates, trg_lengths,
                                      acc, (float*)d_out);
}